// Round 1
// baseline (377.705 us; speedup 1.0000x reference)
//
#include <hip/hip_runtime.h>
#include <hip/hip_bf16.h>

#define NEDGE 800000
#define NNODE 50000
#define DF    64
#define HID   128

using short8 = __attribute__((ext_vector_type(8))) short;
using f32x4  = __attribute__((ext_vector_type(4))) float;

__device__ __forceinline__ unsigned short f2bf(float f) {
    unsigned int u = __builtin_bit_cast(unsigned int, f);
    u += 0x7FFFu + ((u >> 16) & 1u);   // round-to-nearest-even
    return (unsigned short)(u >> 16);
}

__device__ __forceinline__ float silu_f(float v) {
    return v / (1.0f + __expf(-v));
}

// XOR-swizzled byte offset inside a row-major [R][128]-bf16 tile (row stride 256B).
// 16B slot index (k>>3) is XORed with (row&7) -> frag reads are ~2-way conflicts (free).
__device__ __forceinline__ int swz(int r, int k) {
    return (r << 8) + ((((k >> 3) ^ (r & 7)) << 4) | ((k & 7) << 1));
}
__device__ __forceinline__ int swz16(int r, int slot) {
    return (r << 8) + ((slot ^ (r & 7)) << 4);
}

__global__ void __launch_bounds__(256)
gnn_fused(const float* __restrict__ x, const int* __restrict__ ei,
          const float* __restrict__ t,
          const float* __restrict__ W1, const float* __restrict__ b1,
          const float* __restrict__ Wt, const float* __restrict__ bt,
          const float* __restrict__ W2, const float* __restrict__ b2,
          float* __restrict__ out)
{
    extern __shared__ char lds[];
    char* const w1s = lds;            // 32KB: W1^T bf16, swizzled, row = hidden j
    char* const w2s = lds + 32768;    // 32KB: W2^T bf16, swizzled, row = out-dim j
    const int tid  = threadIdx.x;
    const int wave = tid >> 6;
    const int lane = tid & 63;
    char* const hs = lds + 65536 + (wave << 12);  // per-wave 4KB: h[16][128] bf16, swizzled

    // ---- stage W1^T / W2^T into LDS as bf16 (once per block, amortized over tiles)
    for (int idx = tid; idx < HID * HID; idx += 256) {
        const int k = idx >> 7, j = idx & 127;    // W row-major [k][j]
        const int off = swz(j, k);                // store transposed: row j, col k
        *(unsigned short*)(w1s + off) = f2bf(W1[idx]);
        *(unsigned short*)(w2s + off) = f2bf(W2[idx]);
    }

    const int jl   = lane & 15;   // MFMA col / A row within tile
    const int quad = lane >> 4;   // k-group
    float wtj[8], btj[8], b1j[8], b2j[8];
#pragma unroll
    for (int nt = 0; nt < 8; nt++) {
        const int j = nt * 16 + jl;
        wtj[nt] = Wt[j]; btj[nt] = bt[j]; b1j[nt] = b1[j]; b2j[nt] = b2[j];
    }
    __syncthreads();

    const int gwave = (blockIdx.x << 2) + wave;
    const int nwave = gridDim.x << 2;

    // 50000 wave-tiles of 16 edges; fully independent per wave (no barriers in loop)
    for (int tile = gwave; tile < NEDGE / 16; tile += nwave) {
        const int base = tile << 4;

        // ---- A fragments: edge_input[base + (lane&15)][k], k = quad*8 + e + 32*kk
        const int eA = base + jl;
        const int ri = ei[eA];
        const int ci = ei[NEDGE + eA];
        const float* xr = x + ri * DF;
        const float* xc = x + ci * DF;

        short8 a[4];
        const int k0 = quad << 3;
#pragma unroll
        for (int kk = 0; kk < 4; kk++) {
            const float* src = (kk < 2 ? xr : xc) + ((kk & 1) << 5) + k0;
            const f32x4 u = *(const f32x4*)(src);
            const f32x4 v = *(const f32x4*)(src + 4);
            short8 fr;
            fr[0] = (short)f2bf(u[0]); fr[1] = (short)f2bf(u[1]);
            fr[2] = (short)f2bf(u[2]); fr[3] = (short)f2bf(u[3]);
            fr[4] = (short)f2bf(v[0]); fr[5] = (short)f2bf(v[1]);
            fr[6] = (short)f2bf(v[2]); fr[7] = (short)f2bf(v[3]);
            a[kk] = fr;
        }

        // ---- per-lane epilogue rows: edges base + quad*4 + r  (C-layout rows)
        const int er = base + (quad << 2);
        float t4[4]; int ridx[4], cidx[4];
#pragma unroll
        for (int r = 0; r < 4; r++) {
            t4[r]   = t[er + r];
            ridx[r] = ei[er + r];
            cidx[r] = ei[NEDGE + er + r];
        }

        // ---- GEMM1: h = silu(edge_in @ W1 + silu(t*Wt+bt) + b1), store bf16 to hs
#pragma unroll
        for (int nt = 0; nt < 8; nt++) {
            f32x4 acc = {0.f, 0.f, 0.f, 0.f};
            const int j = nt * 16 + jl;
#pragma unroll
            for (int kk = 0; kk < 4; kk++) {
                const short8 bfr = *(const short8*)(w1s + swz16(j, (kk << 2) + quad));
                acc = __builtin_amdgcn_mfma_f32_16x16x32_bf16(a[kk], bfr, acc, 0, 0, 0);
            }
#pragma unroll
            for (int r = 0; r < 4; r++) {
                const float temb = silu_f(fmaf(t4[r], wtj[nt], btj[nt]));
                const float h = silu_f(acc[r] + temb + b1j[nt]);
                *(unsigned short*)(hs + swz((quad << 2) + r, j)) = f2bf(h);
            }
        }

        // ---- A2 fragments: h[lane&15][quad*8 + e + 32*kk] (same wave, LDS-ordered)
        short8 a2[4];
#pragma unroll
        for (int kk = 0; kk < 4; kk++) {
            a2[kk] = *(const short8*)(hs + swz16(jl, (kk << 2) + quad));
        }

        // ---- GEMM2 + bias + atomic scatter.
        // out col = nt*16+jl; nt<4 -> src half (node=row idx), nt>=4 -> tgt half (node=col idx)
#pragma unroll
        for (int nt = 0; nt < 8; nt++) {
            f32x4 acc = {0.f, 0.f, 0.f, 0.f};
            const int j = nt * 16 + jl;
#pragma unroll
            for (int kk = 0; kk < 4; kk++) {
                const short8 bfr = *(const short8*)(w2s + swz16(j, (kk << 2) + quad));
                acc = __builtin_amdgcn_mfma_f32_16x16x32_bf16(a2[kk], bfr, acc, 0, 0, 0);
            }
#pragma unroll
            for (int r = 0; r < 4; r++) {
                const float v = acc[r] + b2j[nt];
                const int node = (nt < 4) ? ridx[r] : cidx[r];
                unsafeAtomicAdd(out + node * DF + (j & 63), v);
            }
        }
    }
}

extern "C" void kernel_launch(void* const* d_in, const int* in_sizes, int n_in,
                              void* d_out, int out_size, void* d_ws, size_t ws_size,
                              hipStream_t stream) {
    const float* x  = (const float*)d_in[0];
    const int*   ei = (const int*)d_in[1];
    const float* t  = (const float*)d_in[2];
    const float* W1 = (const float*)d_in[3];
    const float* b1 = (const float*)d_in[4];
    const float* Wt = (const float*)d_in[5];
    const float* bt = (const float*)d_in[6];
    const float* W2 = (const float*)d_in[7];
    const float* b2 = (const float*)d_in[8];
    float* out = (float*)d_out;

    // zero the accumulation target each call (harness poisons d_out)
    hipMemsetAsync(out, 0, (size_t)out_size * sizeof(float), stream);

    const int ldsBytes = 65536 + 4 * 4096;  // 80KB -> 2 blocks/CU
    hipFuncSetAttribute((const void*)gnn_fused,
                        hipFuncAttributeMaxDynamicSharedMemorySize, ldsBytes);
    hipLaunchKernelGGL(gnn_fused, dim3(1024), dim3(256), ldsBytes, stream,
                       x, ei, t, W1, b1, Wt, bt, W2, b2, out);
}

// Round 3
// 371.919 us; speedup vs baseline: 1.0156x; 1.0156x over previous
//
#include <hip/hip_runtime.h>
#include <hip/hip_bf16.h>

#define NEDGE 800000
#define NNODE 50000
#define DF    64
#define HID   128
#define NTILE (NEDGE / 16)

using short8 = __attribute__((ext_vector_type(8))) short;
using f32x4  = __attribute__((ext_vector_type(4))) float;
using i32x4  = __attribute__((ext_vector_type(4))) int;

union P8 { unsigned int u[4]; short8 s; };

__device__ __forceinline__ unsigned int pk2(float lo, float hi) {
    union { __hip_bfloat162 p; unsigned int u; } c;
    c.p = __float22bfloat162_rn(float2{lo, hi});
    return c.u;
}

__device__ __forceinline__ short8 cvt8(f32x4 u, f32x4 v) {
    P8 p;
    p.u[0] = pk2(u[0], u[1]);
    p.u[1] = pk2(u[2], u[3]);
    p.u[2] = pk2(v[0], v[1]);
    p.u[3] = pk2(v[2], v[3]);
    return p.s;
}

__device__ __forceinline__ unsigned short bf1(float f) {
    union { __hip_bfloat16 b; unsigned short u; } c;
    c.b = __float2bfloat16(f);
    return c.u;
}

__device__ __forceinline__ float silu_f(float v) {
    return v / (1.0f + __expf(-v));
}

// XOR-swizzled byte offset inside a row-major [R][128]-bf16 tile (row stride 256B).
__device__ __forceinline__ int swz(int r, int k) {
    return (r << 8) + ((((k >> 3) ^ (r & 7)) << 4) | ((k & 7) << 1));
}
__device__ __forceinline__ int swz16(int r, int slot) {
    return (r << 8) + ((slot ^ (r & 7)) << 4);
}

__global__ void __launch_bounds__(256, 2)
gnn_fused(const float* __restrict__ x, const int* __restrict__ ei,
          const float* __restrict__ t,
          const float* __restrict__ W1, const float* __restrict__ b1,
          const float* __restrict__ Wt, const float* __restrict__ bt,
          const float* __restrict__ W2, const float* __restrict__ b2,
          float* __restrict__ out)
{
    extern __shared__ char lds[];
    char* const w1s = lds;            // 32KB: W1^T bf16, swizzled, row = hidden j
    char* const w2s = lds + 32768;    // 32KB: W2^T bf16, swizzled, row = out-dim j
    const int tid  = threadIdx.x;
    const int wave = tid >> 6;
    const int lane = tid & 63;
    char* const hs = lds + 65536 + (wave << 12);  // per-wave 4KB: h[16][128] bf16

    for (int idx = tid; idx < HID * HID; idx += 256) {
        const int k = idx >> 7, j = idx & 127;    // W row-major [k][j]
        const int off = swz(j, k);                // store transposed
        *(unsigned short*)(w1s + off) = bf1(W1[idx]);
        *(unsigned short*)(w2s + off) = bf1(W2[idx]);
    }

    const int jl   = lane & 15;   // MFMA col / A row within tile
    const int quad = lane >> 4;   // k-group
    const int k0   = quad << 3;
    float wtj[8], btj[8], b1j[8], b2j[8];
#pragma unroll
    for (int nt = 0; nt < 8; nt++) {
        const int j = nt * 16 + jl;
        wtj[nt] = Wt[j]; btj[nt] = bt[j]; b1j[nt] = b1[j]; b2j[nt] = b2[j];
    }
    __syncthreads();

    const int gwave = (blockIdx.x << 2) + wave;
    const int nwave = gridDim.x << 2;

#define ISSUE_EI(T, RA, CA) { const int e_ = (T) * 16 + jl; RA = ei[e_]; CA = ei[NEDGE + e_]; }
#define ISSUE_X(RA, CA, X_) { \
    const float* xr_ = x + (RA) * DF + k0; \
    const float* xc_ = x + (CA) * DF + k0; \
    X_[0] = *(const f32x4*)(xr_);      X_[1] = *(const f32x4*)(xr_ + 4);  \
    X_[2] = *(const f32x4*)(xr_ + 32); X_[3] = *(const f32x4*)(xr_ + 36); \
    X_[4] = *(const f32x4*)(xc_);      X_[5] = *(const f32x4*)(xc_ + 4);  \
    X_[6] = *(const f32x4*)(xc_ + 32); X_[7] = *(const f32x4*)(xc_ + 36); }
#define ISSUE_EP(T, T4_, RI_, CI_) { const int er_ = (T) * 16 + (quad << 2); \
    T4_ = *(const f32x4*)(t + er_); \
    RI_ = *(const i32x4*)(ei + er_); \
    CI_ = *(const i32x4*)(ei + NEDGE + er_); }

    // ---- pipeline prologue
    int tile = gwave;
    int riA, ciA;  ISSUE_EI(tile, riA, ciA);
    f32x4 X[8];    ISSUE_X(riA, ciA, X);
    f32x4 T4; i32x4 RI, CI; ISSUE_EP(tile, T4, RI, CI);
    int tn  = tile + nwave;
    int tns = (tn < NTILE) ? tn : gwave;
    int riA_n, ciA_n; ISSUE_EI(tns, riA_n, ciA_n);

    while (tile < NTILE) {
        // ---- issue prefetch for t+1 (x, epilogue) and t+2 (edge indices)
        f32x4 Xn[8]; ISSUE_X(riA_n, ciA_n, Xn);
        f32x4 T4n; i32x4 RIn, CIn; ISSUE_EP(tns, T4n, RIn, CIn);
        const int t2  = tn + nwave;
        const int t2s = (t2 < NTILE) ? t2 : gwave;
        int riA_nn, ciA_nn; ISSUE_EI(t2s, riA_nn, ciA_nn);

        // ---- A fragments from prefetched x
        short8 a[4];
#pragma unroll
        for (int kk = 0; kk < 4; kk++) a[kk] = cvt8(X[2 * kk], X[2 * kk + 1]);

        // ---- epilogue base pointers (immediate-offset atomics)
        float* pS[4]; float* pT[4];
#pragma unroll
        for (int r = 0; r < 4; r++) {
            pS[r] = out + RI[r] * DF + jl;
            pT[r] = out + CI[r] * DF + jl;
        }

        // ---- GEMM1: h = silu(edge_in @ W1 + silu(t*Wt+bt) + b1) -> hs (bf16)
#pragma unroll
        for (int nt = 0; nt < 8; nt++) {
            f32x4 acc = {0.f, 0.f, 0.f, 0.f};
            const int j = nt * 16 + jl;
#pragma unroll
            for (int kk = 0; kk < 4; kk++) {
                const short8 bfr = *(const short8*)(w1s + swz16(j, (kk << 2) + quad));
                acc = __builtin_amdgcn_mfma_f32_16x16x32_bf16(a[kk], bfr, acc, 0, 0, 0);
            }
#pragma unroll
            for (int r = 0; r < 4; r++) {
                const float temb = silu_f(fmaf(T4[r], wtj[nt], btj[nt]));
                const float h = silu_f(acc[r] + temb + b1j[nt]);
                *(unsigned short*)(hs + swz((quad << 2) + r, j)) = bf1(h);
            }
        }

        // ---- A2 fragments from hs
        short8 a2[4];
#pragma unroll
        for (int kk = 0; kk < 4; kk++) {
            a2[kk] = *(const short8*)(hs + swz16(jl, (kk << 2) + quad));
        }

        // ---- GEMM2 + bias + atomic scatter (imm-offset per nt)
#pragma unroll
        for (int nt = 0; nt < 8; nt++) {
            f32x4 acc = {0.f, 0.f, 0.f, 0.f};
            const int j = nt * 16 + jl;
#pragma unroll
            for (int kk = 0; kk < 4; kk++) {
                const short8 bfr = *(const short8*)(w2s + swz16(j, (kk << 2) + quad));
                acc = __builtin_amdgcn_mfma_f32_16x16x32_bf16(a2[kk], bfr, acc, 0, 0, 0);
            }
#pragma unroll
            for (int r = 0; r < 4; r++) {
                const float v = acc[r] + b2j[nt];
                if (nt < 4) unsafeAtomicAdd(pS[r] + nt * 16, v);
                else        unsafeAtomicAdd(pT[r] + (nt - 4) * 16, v);
            }
        }

        // ---- rotate pipeline state
        tile = tn; tn = t2; tns = t2s;
#pragma unroll
        for (int i = 0; i < 8; i++) X[i] = Xn[i];
        T4 = T4n; RI = RIn; CI = CIn;
        riA_n = riA_nn; ciA_n = ciA_nn;
    }
#undef ISSUE_EI
#undef ISSUE_X
#undef ISSUE_EP
}

extern "C" void kernel_launch(void* const* d_in, const int* in_sizes, int n_in,
                              void* d_out, int out_size, void* d_ws, size_t ws_size,
                              hipStream_t stream) {
    const float* x  = (const float*)d_in[0];
    const int*   ei = (const int*)d_in[1];
    const float* t  = (const float*)d_in[2];
    const float* W1 = (const float*)d_in[3];
    const float* b1 = (const float*)d_in[4];
    const float* Wt = (const float*)d_in[5];
    const float* bt = (const float*)d_in[6];
    const float* W2 = (const float*)d_in[7];
    const float* b2 = (const float*)d_in[8];
    float* out = (float*)d_out;

    (void)hipMemsetAsync(out, 0, (size_t)out_size * sizeof(float), stream);

    const int ldsBytes = 65536 + 4 * 4096;  // 80KB -> 2 blocks/CU
    (void)hipFuncSetAttribute((const void*)gnn_fused,
                              hipFuncAttributeMaxDynamicSharedMemorySize, ldsBytes);
    hipLaunchKernelGGL(gnn_fused, dim3(512), dim3(256), ldsBytes, stream,
                       x, ei, t, W1, b1, Wt, bt, W2, b2, out);
}